// Round 17
// baseline (1064.421 us; speedup 1.0000x reference)
//
#include <hip/hip_runtime.h>
#include <hip/hip_fp8.h>
#include <math.h>

#define NN 10000
#define NE 320000
#define NEP (NE + 64)      // padded ebuf row stride (ushort elements)
#define PI_F 3.14159265358979323846f

typedef __attribute__((ext_vector_type(8))) short short8x;
typedef __attribute__((ext_vector_type(4))) float float4x;

#if defined(__has_builtin)
#if __has_builtin(__builtin_amdgcn_cvt_pk_fp8_f32) && __has_builtin(__builtin_amdgcn_cvt_f32_fp8)
#define HW_FP8 1
#endif
#endif

__device__ __forceinline__ unsigned short f2b(float f) {
    unsigned b = __float_as_uint(f);
    return (unsigned short)((b + 0x7FFFu + ((b >> 16) & 1u)) >> 16);
}
__device__ __forceinline__ float b2f(unsigned short u) {
    return __uint_as_float(((unsigned)u) << 16);
}
__device__ __forceinline__ float silu(float x) {
    return x / (1.f + __expf(-x));
}
__device__ __forceinline__ unsigned char f2e4(float f) {
#ifdef HW_FP8
    int r = __builtin_amdgcn_cvt_pk_fp8_f32(f, f, 0, false);
    return (unsigned char)(r & 0xff);
#else
    __hip_fp8_e4m3 q(f);
    return (unsigned char)q.__x;
#endif
}
__device__ __forceinline__ unsigned short pk2(float lo, float hi) {
#ifdef HW_FP8
    int r = __builtin_amdgcn_cvt_pk_fp8_f32(lo, hi, 0, false);
    return (unsigned short)(r & 0xffff);
#else
    return (unsigned short)((unsigned)f2e4(lo) | ((unsigned)f2e4(hi) << 8));
#endif
}
__device__ __forceinline__ float e42f(unsigned char v) {
#ifdef HW_FP8
    return __builtin_amdgcn_cvt_f32_fp8((int)v, 0);
#else
    __hip_fp8_e4m3 q;
    q.__x = (__hip_fp8_storage_t)v;
    return (float)q;
#endif
}
// byte-select decode: builtin requires IMMEDIATE sel -> switch with literal cases
__device__ __forceinline__ float e4sel(unsigned word, int sel) {
#ifdef HW_FP8
    switch (sel & 3) {
        case 0:  return __builtin_amdgcn_cvt_f32_fp8((int)word, 0);
        case 1:  return __builtin_amdgcn_cvt_f32_fp8((int)word, 1);
        case 2:  return __builtin_amdgcn_cvt_f32_fp8((int)word, 2);
        default: return __builtin_amdgcn_cvt_f32_fp8((int)word, 3);
    }
#else
    return e42f((unsigned char)((word >> (8*(sel & 3))) & 0xffu));
#endif
}

// ---------------- K = Newton-Schulz semi-unitary (16x2) ----------------
__global__ void k_newton_kernel(const float* __restrict__ PU, float* __restrict__ Kout)
{
    if (threadIdx.x != 0 || blockIdx.x != 0) return;
    float K[32];
    float nrm = 0.f;
    for (int i = 0; i < 32; ++i) { K[i] = PU[i]; nrm += K[i]*K[i]; }
    float inv = 1.0f / sqrtf(nrm);
    for (int i = 0; i < 32; ++i) K[i] *= inv;
    for (int it = 0; it < 10; ++it) {
        float m00 = 0.f, m01 = 0.f, m11 = 0.f;
        for (int u = 0; u < 16; ++u) {
            float a = K[2*u], b = K[2*u+1];
            m00 += a*a; m01 += a*b; m11 += b*b;
        }
        for (int u = 0; u < 16; ++u) {
            float a = K[2*u], b = K[2*u+1];
            K[2*u]   = 1.5f*a - 0.5f*(a*m00 + b*m01);
            K[2*u+1] = 1.5f*b - 0.5f*(a*m01 + b*m11);
        }
    }
    for (int i = 0; i < 32; ++i) Kout[i] = K[i];
}

// ---------------- merged init: x_pad + yv init + zero ys0/ys1/fsb ----------------
__global__ __launch_bounds__(256) void init_all_kernel(
    const float* __restrict__ x, const float* __restrict__ K,
    float* __restrict__ xp, float* __restrict__ yv0, float* __restrict__ yv1,
    float* __restrict__ ys0, float* __restrict__ ys1, float* __restrict__ fsb)
{
    int tid = blockIdx.x*256 + threadIdx.x;
    if (tid < NN*8) {
        int n = tid >> 3, c = tid & 7;
        xp[tid] = (c < 6) ? x[n*6 + c] : 0.f;
        return;
    }
    int t2 = tid - NN*8;
    if (t2 < NN*48) {
        int n = t2/48, j = t2%48, u = j/3, m = j%3;
        float v = K[2*u]*x[n*6+m] + K[2*u+1]*x[n*6+3+m];
        yv0[t2] = v; yv1[t2] = v;
        return;
    }
    t2 -= NN*48;
    if (t2 < NN*64) { ys0[t2] = 0.f; ys1[t2] = 0.f; fsb[t2] = 0.f; }
}

// ---------------- layer-0 fvv init (fs0 = 0 since ys0 = 0) ----------------
__global__ void init_fvv_kernel(const float* __restrict__ yv, const int* __restrict__ types,
                                const float* __restrict__ lin1vT0, float* __restrict__ fvv)
{
    int tid = blockIdx.x*blockDim.x + threadIdx.x;
    if (tid >= NN*48) return;
    int n = tid/48, j = tid%48, o = j/3, m = j%3;
    int t = types[n];
    const float* W = lin1vT0 + (size_t)t*256;
    float acc = 0.f;
    #pragma unroll
    for (int i = 0; i < 16; ++i) acc += yv[n*48 + i*3 + m]*W[i*16 + o];
    fvv[tid] = acc;
}

// ---------------- per-type effective weights (device body) ----------------
__device__ __forceinline__ void be_body(const float* __restrict__ W, const float* __restrict__ emb,
                                        float* __restrict__ out, int id, int O, int I, float scale)
{
    int o = id % O; int r = id / O;
    int i = r % I; r /= I;
    int t = r % 100; int l = r / 100;
    const float* w  = W + (((size_t)l*O + o)*I + i)*32;
    const float* em = emb + (size_t)t*32;
    float acc = 0.f;
    #pragma unroll
    for (int e = 0; e < 32; ++e) acc += w[e]*em[e];
    out[id] = acc*scale;
}

// ---------------- merged weight prep ----------------
#define PREP_TOTAL (2048000 + 1638400 + 512000 + 512000 + 102400 + 102400 + 49152 + 16384 + 16384 + 8192 + 1024)
__global__ __launch_bounds__(256) void prep_kernel(
    const float* __restrict__ lin1_Ws, const float* __restrict__ lin1_Wv,
    const float* __restrict__ sc_Ws,   const float* __restrict__ sc_Wv,
    const float* __restrict__ lin2_Ws, const float* __restrict__ lin2_Wv,
    const float* __restrict__ si_Ws,   const float* __restrict__ si_Wv,
    const float* __restrict__ fc_W1,   const float* __restrict__ fc_W2,
    const float* __restrict__ fc_W3,   const float* __restrict__ emb,
    float* __restrict__ lin1sT, float* __restrict__ lin1vT,
    float* __restrict__ scsT,   float* __restrict__ scvT,
    float* __restrict__ lin2sT, float* __restrict__ lin2vT,
    float* __restrict__ siWsT,  float* __restrict__ siWvT,
    unsigned short* __restrict__ w1bp, unsigned short* __restrict__ w2bp,
    unsigned short* __restrict__ w3bf)
{
    const float s2048 = 0.022097086912079608f;   // 1/sqrt(2048)
    const float s512  = 0.044194173824159216f;   // 1/sqrt(512)
    const float s2560 = 0.019764235376052372f;   // 1/sqrt(2560)
    int tid = blockIdx.x*256 + threadIdx.x;
    if (tid < 2048000) { be_body(sc_Ws,   emb, scsT,   tid, 80, 64, s2048); return; }
    tid -= 2048000;
    if (tid < 1638400) { be_body(lin1_Ws, emb, lin1sT, tid, 64, 64, s2048); return; }
    tid -= 1638400;
    if (tid < 512000)  { be_body(lin2_Ws, emb, lin2sT, tid, 80, 16, s512);  return; }
    tid -= 512000;
    if (tid < 512000)  { be_body(lin2_Wv, emb, lin2vT, tid, 16, 80, s2560); return; }
    tid -= 512000;
    if (tid < 102400)  { be_body(lin1_Wv, emb, lin1vT, tid, 16, 16, s512);  return; }
    tid -= 102400;
    if (tid < 102400)  { be_body(sc_Wv,   emb, scvT,   tid, 16, 16, s512);  return; }
    tid -= 102400;
    if (tid < 49152) {
        int o = tid % 64; int r = tid / 64; int i = r % 192; int l = r / 192;
        w3bf[tid] = f2b(fc_W3[((size_t)l*64 + o)*192 + i]);
        return;
    }
    tid -= 49152;
    if (tid < 16384) {
        int o = tid % 64; int r = tid / 64; int i = r % 64; int l = r / 64;
        siWsT[tid] = si_Ws[((size_t)l*64 + o)*64 + i]*0.125f;
        return;
    }
    tid -= 16384;
    if (tid < 16384) {
        int kk = tid % 64; int r = tid / 64; int n = r % 64; int l = r / 64;
        w2bp[tid] = f2b(fc_W2[((size_t)l*64 + kk)*64 + n]);
        return;
    }
    tid -= 16384;
    if (tid < 8192) {
        int kk = tid % 32; int r = tid / 32; int n = r % 64; int l = r / 64;
        float v = (kk < 16) ? fc_W1[((size_t)l*16 + kk)*64 + n] : 0.f;
        w1bp[tid] = f2b(v);
        return;
    }
    tid -= 8192;
    if (tid < 1024) {
        int o = tid % 16; int r = tid / 16; int i = r % 16; int l = r / 16;
        siWvT[tid] = si_Wv[((size_t)l*16 + o)*16 + i]*0.25f;
    }
}

// ---------------- counting sort by dst ----------------
__global__ void hist_kernel(const int* __restrict__ dst, int* __restrict__ deg)
{
    int e = blockIdx.x*256 + threadIdx.x;
    if (e < NE) atomicAdd(&deg[dst[e]], 1);
}

__global__ __launch_bounds__(256) void scan_kernel(const int* __restrict__ deg,
                                                   int* __restrict__ segoff,
                                                   int* __restrict__ cursor)
{
    __shared__ int part[256];
    int tid = threadIdx.x;
    int base = tid*40;
    int s = 0;
    for (int i = 0; i < 40; ++i) { int idx = base+i; if (idx < NN) s += deg[idx]; }
    part[tid] = s;
    __syncthreads();
    for (int o = 1; o < 256; o <<= 1) {
        int v = (tid >= o) ? part[tid-o] : 0;
        __syncthreads();
        part[tid] += v;
        __syncthreads();
    }
    int excl = part[tid] - s;
    for (int i = 0; i < 40; ++i) {
        int idx = base+i;
        if (idx < NN) { segoff[idx] = excl; cursor[idx] = excl; excl += deg[idx]; }
        else if (idx == NN) { segoff[NN] = excl; }
    }
}

__global__ void scatter_kernel(const int* __restrict__ src, const int* __restrict__ dst,
                               int* __restrict__ cursor,
                               int* __restrict__ srcs, int* __restrict__ dsts)
{
    int e = blockIdx.x*256 + threadIdx.x;
    if (e >= NE) return;
    int d = dst[e];
    int p = atomicAdd(&cursor[d], 1);
    srcs[p] = src[e]; dsts[p] = d;
}

// ---------------- node type-sort: one block, LDS counting sort over 100 types ----------------
__global__ __launch_bounds__(256) void nsort_kernel(const int* __restrict__ types,
                                                    int* __restrict__ nperm)
{
    __shared__ int hist[100], base[100];
    int t = threadIdx.x;
    if (t < 100) hist[t] = 0;
    __syncthreads();
    for (int n = t; n < NN; n += 256) atomicAdd(&hist[types[n]], 1);
    __syncthreads();
    if (t == 0) {
        int acc = 0;
        for (int i = 0; i < 100; ++i) { base[i] = acc; acc += hist[i]; }
    }
    __syncthreads();
    for (int n = t; n < NN; n += 256) {
        int p = atomicAdd(&base[types[n]], 1);
        nperm[p] = n;
    }
}

// ---------------- fused edge kernel: geometry(4 thr/edge) -> MFMA MLP chain -> TP -> ebuf ----------------
// ebuf layout: 128 ushort rows; row r packs fp8(comp 2r) | fp8(comp 2r+1)<<8.
__global__ __launch_bounds__(256, 8) void edge_fused_kernel(
    const float* __restrict__ xp,
    const int* __restrict__ srcs, const int* __restrict__ dsts,
    const unsigned short* __restrict__ w1b,   // [64 n][32 k] bf16 (k 16..31 zero)
    const float* __restrict__ b1,
    const unsigned short* __restrict__ w2b,   // [64 n][64 k] bf16
    const float* __restrict__ b2,
    const unsigned short* __restrict__ w3b,   // [192 n][64 k] bf16
    const float* __restrict__ b3,
    const float* __restrict__ fs, const float* __restrict__ fvv,
    unsigned short* __restrict__ ebuf)
{
    __shared__ __align__(16) unsigned char smem[64*196];   // wbuf fp8 region; hbuf aliases front
    __shared__ float abuf[64*6];
    unsigned short* hbuf = (unsigned short*)smem;          // [64][72] bf16 (9216 B)
    unsigned char*  wbuf = smem;                           // [64][196] fp8 (12544 B)
    int lane = threadIdx.x & 63;
    int wid  = threadIdx.x >> 6;
    int eblk = blockIdx.x * 64;
    int row16 = lane & 15, quad = lane >> 4;
    int erow = 16*wid + row16;

    // ---- phase G: 4 threads per edge (thread j: branch j>>1, bessel-half j&1) ----
    {
        int c = threadIdx.x;
        int e = c >> 2, j = c & 3;
        int p = eblk + e;
        int s = srcs[p], d = dsts[p];
        const float4* xs4 = (const float4*)(xp + (size_t)s*8);
        const float4* xd4 = (const float4*)(xp + (size_t)d*8);
        float d0, d1, d2;
        if (j < 2) {
            float4 xsa = xs4[0], xda = xd4[0];
            d0 = xsa.x-xda.x; d1 = xsa.y-xda.y; d2 = xsa.z-xda.z;
        } else {
            float4 xsa = xs4[0], xsb = xs4[1];
            float4 xda = xd4[0], xdb = xd4[1];
            d0 = xsa.w-xda.w; d1 = xsb.x-xdb.x; d2 = xsb.y-xdb.y;
        }
        float r = sqrtf(d0*d0 + d1*d1 + d2*d2);
        float invr = 1.0f/r;
        if ((j & 1) == 0) {   // one thread per branch: cutoff + attr
            float u = 0.8f*r - 2.0f;
            float cut = (u > 0.f) ? 0.f : ((u < -1.f) ? 1.f : 0.5f*(1.f - __cosf(PI_F*u)));
            float sc = 1.7320508075688772f*cut*invr;
            float* ab = abuf + e*6 + (j >> 1)*3;
            ab[0] = sc*d0; ab[1] = sc*d1; ab[2] = sc*d2;
        }
        float fsc = 2.5298221281347035f*invr;
        int kb = (j & 1)*4;   // bessel index base within branch
        float v0 = fsc*__sinf((kb+1)*1.2566370614359172f*r);
        float v1 = fsc*__sinf((kb+2)*1.2566370614359172f*r);
        float v2 = fsc*__sinf((kb+3)*1.2566370614359172f*r);
        float v3 = fsc*__sinf((kb+4)*1.2566370614359172f*r);
        uint2 q;
        q.x = (unsigned)f2b(v0) | ((unsigned)f2b(v1) << 16);
        q.y = (unsigned)f2b(v2) | ((unsigned)f2b(v3) << 16);
        *(uint2*)(hbuf + e*72 + j*4) = q;            // ef shorts [j*4, j*4+4)
        uint2 z; z.x = 0; z.y = 0;
        *(uint2*)(hbuf + e*72 + 16 + j*4) = z;       // K-pad zeros shorts [16+j*4, ..)
    }
    __syncthreads();   // hbuf rows now written cross-wave

    // ---- GEMM1: h1 = silu(ef @ W1 + b1), K=32 ----
    {
        short8x a = *(const short8x*)(hbuf + erow*72 + quad*8);
        float4x c[4];
        #pragma unroll
        for (int nt = 0; nt < 4; ++nt) {
            short8x b = *(const short8x*)(w1b + ((size_t)(nt*16 + row16))*32 + quad*8);
            c[nt] = __builtin_amdgcn_mfma_f32_16x16x32_bf16(a, b, (float4x){0.f,0.f,0.f,0.f}, 0, 0, 0);
        }
        #pragma unroll
        for (int nt = 0; nt < 4; ++nt) {
            float bias = b1[nt*16 + row16];
            #pragma unroll
            for (int r = 0; r < 4; ++r) {
                float h = silu(c[nt][r] + bias);
                hbuf[(16*wid + quad*4 + r)*72 + nt*16 + row16] = f2b(h);
            }
        }
    }
    // ---- GEMM2: h2 = silu(h1 @ W2 + b2), K=64 ----
    {
        short8x a0v = *(const short8x*)(hbuf + erow*72 + 0*32 + quad*8);
        short8x a1v = *(const short8x*)(hbuf + erow*72 + 1*32 + quad*8);
        float4x c[4];
        #pragma unroll
        for (int nt = 0; nt < 4; ++nt) {
            short8x b0 = *(const short8x*)(w2b + ((size_t)(nt*16 + row16))*64 + 0*32 + quad*8);
            float4x t = __builtin_amdgcn_mfma_f32_16x16x32_bf16(a0v, b0, (float4x){0.f,0.f,0.f,0.f}, 0, 0, 0);
            short8x b1v = *(const short8x*)(w2b + ((size_t)(nt*16 + row16))*64 + 1*32 + quad*8);
            c[nt] = __builtin_amdgcn_mfma_f32_16x16x32_bf16(a1v, b1v, t, 0, 0, 0);
        }
        #pragma unroll
        for (int nt = 0; nt < 4; ++nt) {
            float bias = b2[nt*16 + row16];
            #pragma unroll
            for (int r = 0; r < 4; ++r) {
                float h = silu(c[nt][r] + bias);
                hbuf[(16*wid + quad*4 + r)*72 + nt*16 + row16] = f2b(h);
            }
        }
    }
    // ---- GEMM3: w = h2 @ W3 -> fp8 into wbuf (aliases hbuf; pre-read A then barrier) ----
    {
        short8x a0v = *(const short8x*)(hbuf + erow*72 + 0*32 + quad*8);
        short8x a1v = *(const short8x*)(hbuf + erow*72 + 1*32 + quad*8);
        __syncthreads();   // all waves hold their A-fragments; hbuf region may now be overwritten
        float4x acc[12];
        #pragma unroll
        for (int nt = 0; nt < 12; ++nt) {
            short8x b0 = *(const short8x*)(w3b + ((size_t)(nt*16 + row16))*64 + 0*32 + quad*8);
            float4x t = __builtin_amdgcn_mfma_f32_16x16x32_bf16(a0v, b0, (float4x){0.f,0.f,0.f,0.f}, 0, 0, 0);
            short8x b1v = *(const short8x*)(w3b + ((size_t)(nt*16 + row16))*64 + 1*32 + quad*8);
            acc[nt] = __builtin_amdgcn_mfma_f32_16x16x32_bf16(a1v, b1v, t, 0, 0, 0);
        }
        #pragma unroll
        for (int nt = 0; nt < 12; ++nt) {
            #pragma unroll
            for (int r = 0; r < 4; ++r) {
                wbuf[(16*wid + quad*4 + r)*196 + nt*16 + row16] = f2e4(acc[nt][r]);
            }
        }
    }
    __syncthreads();

    // ---- TP phase: thread (edge = lane, part = wid) ----
    int p = eblk + lane;
    const unsigned* wrow32 = (const unsigned*)(wbuf + lane*196);  // 196 % 4 == 0
    float a0[3], a1[3];
    {
        const float* ab = abuf + lane*6;
        a0[0] = ab[0]; a0[1] = ab[1]; a0[2] = ab[2];
        a1[0] = ab[3]; a1[1] = ab[4]; a1[2] = ab[5];
    }
    int s = srcs[p];
    // o1: comps [48*wid, 48*wid+48) -> pair rows [24*wid, 24*wid+24)
    {
        int U0 = 16*wid;
        int rbase = 24*wid;
        float fsr[16];
        {
            const float4* f4 = (const float4*)(fs + (size_t)s*64 + U0);
            #pragma unroll
            for (int g = 0; g < 4; ++g) {
                float4 t = f4[g];
                fsr[4*g+0] = t.x; fsr[4*g+1] = t.y; fsr[4*g+2] = t.z; fsr[4*g+3] = t.w;
            }
        }
        float carry = 0.f;
        #pragma unroll
        for (int uu = 0; uu < 16; ++uu) {
            int u = U0 + uu;
            float su = fsr[uu]*0.125f;   // 1/sqrt(2) * 1/sqrt(32)
            unsigned word = wrow32[u >> 1];
            float wa = e4sel(word, (uu & 1)*2)     + b3[2*u];
            float wb = e4sel(word, (uu & 1)*2 + 1) + b3[2*u+1];
            float q0 = su*(wa*a0[0] + wb*a1[0]);
            float q1 = su*(wa*a0[1] + wb*a1[1]);
            float q2 = su*(wa*a0[2] + wb*a1[2]);
            if ((uu & 1) == 0) {
                ebuf[(size_t)(rbase + (3*uu)/2)*NEP + p] = pk2(q0, q1);
                carry = q2;
            } else {
                ebuf[(size_t)(rbase + (3*uu-1)/2)*NEP + p] = pk2(carry, q0);
                ebuf[(size_t)(rbase + (3*uu+1)/2)*NEP + p] = pk2(q1, q2);
            }
        }
    }
    // o2 + o3
    {
        int U0 = 4*wid;
        float fvr[12];
        {
            const float4* f4 = (const float4*)(fvv + (size_t)s*48 + 3*U0);
            #pragma unroll
            for (int g = 0; g < 3; ++g) {
                float4 t = f4[g];
                fvr[4*g+0] = t.x; fvr[4*g+1] = t.y; fvr[4*g+2] = t.z; fvr[4*g+3] = t.w;
            }
        }
        int r2base = 96 + 2*wid;
        int r3base = 104 + 6*wid;
        float o2v[4];
        float carry = 0.f;
        #pragma unroll
        for (int uu = 0; uu < 4; ++uu) {
            int u = U0 + uu;
            float v0 = fvr[uu*3+0], v1 = fvr[uu*3+1], v2 = fvr[uu*3+2];
            unsigned w2w = wrow32[32 + (u >> 1)];
            unsigned w3w = wrow32[40 + (u >> 1)];
            float w2a = e4sel(w2w, (uu & 1)*2)     + b3[128+2*u];
            float w2b = e4sel(w2w, (uu & 1)*2 + 1) + b3[129+2*u];
            float w3a = e4sel(w3w, (uu & 1)*2)     + b3[160+2*u];
            float w3b = e4sel(w3w, (uu & 1)*2 + 1) + b3[161+2*u];
            float dd0 = v0*a0[0] + v1*a0[1] + v2*a0[2];
            float dd1 = v0*a1[0] + v1*a1[1] + v2*a1[2];
            o2v[uu] = (w2a*dd0 + w2b*dd1)*0.07216878364870323f;  // 1/sqrt(192)
            float c0x = v1*a0[2]-v2*a0[1], c0y = v2*a0[0]-v0*a0[2], c0z = v0*a0[1]-v1*a0[0];
            float c1x = v1*a1[2]-v2*a1[1], c1y = v2*a1[0]-v0*a1[2], c1z = v0*a1[1]-v1*a1[0];
            float q0 = 0.08838834764831845f*(w3a*c0x + w3b*c1x);  // 1/sqrt(128)
            float q1 = 0.08838834764831845f*(w3a*c0y + w3b*c1y);
            float q2 = 0.08838834764831845f*(w3a*c0z + w3b*c1z);
            if ((uu & 1) == 0) {
                ebuf[(size_t)(r3base + (3*uu)/2)*NEP + p] = pk2(q0, q1);
                carry = q2;
            } else {
                ebuf[(size_t)(r3base + (3*uu-1)/2)*NEP + p] = pk2(carry, q0);
                ebuf[(size_t)(r3base + (3*uu+1)/2)*NEP + p] = pk2(q1, q2);
            }
        }
        ebuf[(size_t)(r2base + 0)*NEP + p] = pk2(o2v[0], o2v[1]);
        ebuf[(size_t)(r2base + 1)*NEP + p] = pk2(o2v[2], o2v[3]);
    }
}

// ---------------- segment-sum via LDS transpose tiles (packed fp8-pair rows, pairwise scan) ----------------
__global__ __launch_bounds__(256) void segsum_kernel(
    const unsigned short* __restrict__ ebuf,
    const int* __restrict__ segoff,
    float* __restrict__ mid)
{
    __shared__ int sbnd[18];
    __shared__ unsigned short stile[256*66];
    int c = threadIdx.x;
    int lane = c & 63, wid = c >> 6;
    int n0 = blockIdx.x * 16;
    if (c < 17) sbnd[c] = segoff[n0 + c];
    else if (c == 17) sbnd[17] = 0x7fffffff;
    __syncthreads();
    int P0 = sbnd[0], P1 = sbnd[16];
    int A = P0 & ~63;
    float cur = 0.f;
    int seg = 0;
    int bnext = sbnd[1];
    const unsigned short* row = stile + c*66;
    for (int base = A; base < P1; base += 64) {
        {
            const unsigned short* src = ebuf + (size_t)(32*wid)*NEP + base + lane;
            unsigned short* dst = stile + (64*wid)*66 + lane;
            #pragma unroll
            for (int rr = 0; rr < 32; ++rr) {
                unsigned v = (unsigned)src[(size_t)rr*NEP];
                dst[(2*rr  )*66] = f2b(e4sel(v, 0));
                dst[(2*rr+1)*66] = f2b(e4sel(v, 1));
            }
        }
        __syncthreads();
        int e0 = (base < P0) ? P0 : base;
        int e1 = (base + 64 < P1) ? (base + 64) : P1;
        int e = e0;
        while (e < e1) {
            int stop = (bnext < e1) ? bnext : e1;
            if (((e - base) & 1) && e < stop) { cur += b2f(row[e - base]); ++e; }
            for (; e + 2 <= stop; e += 2) {
                unsigned v = *(const unsigned*)(row + (e - base));
                cur += b2f((unsigned short)(v & 0xffffu)) + b2f((unsigned short)(v >> 16));
            }
            if (e < stop) { cur += b2f(row[e - base]); ++e; }
            if (e == bnext) {
                mid[(size_t)(n0 + seg)*256 + c] = cur;
                cur = 0.f; ++seg; bnext = sbnd[seg + 1];
            }
        }
        __syncthreads();
    }
    while (seg < 16) {
        mid[(size_t)(n0 + seg)*256 + c] = cur;
        cur = 0.f; ++seg;
    }
}

// ---------------- node update + fused next-layer lin1 (type-sorted order) ----------------
__global__ __launch_bounds__(256) void node_update_kernel(
    const float* __restrict__ ys, const float* __restrict__ yv,
    float* __restrict__ ys_old, float* __restrict__ yv_old,
    const float* __restrict__ mid,
    const int* __restrict__ types, const int* __restrict__ nperm,
    const float* __restrict__ scsT, const float* __restrict__ scvT,
    const float* __restrict__ lin2sT, const float* __restrict__ lin2vT,
    const float* __restrict__ siWsT, const float* __restrict__ siWvT,
    const float* __restrict__ lin1sTn, const float* __restrict__ lin1vTn,
    const float* __restrict__ Kbuf,
    const float* __restrict__ hv, const float* __restrict__ mixv, int layer,
    float* __restrict__ fs_out, float* __restrict__ fvv_out,
    float* __restrict__ xpad, float* __restrict__ dout)
{
    int n = nperm[blockIdx.x];
    int lane = threadIdx.x;
    __shared__ float ys_l[64], yv_l[48], mids[16], midv[240];
    __shared__ float conv_s[80], conv_v[48], sis_l[64], siv_l[48], ysn[64], yvn[48];
    int t = types[n];
    {
        float v = mid[(size_t)n*256 + lane];
        if (lane < 192) midv[lane] = v;
        else if (lane < 208) mids[lane-192] = v;
        else midv[192 + (lane-208)] = v;
    }
    if (lane < 64) ys_l[lane] = ys[n*64 + lane];
    else if (lane < 112) yv_l[lane-64] = yv[n*48 + (lane-64)];
    __syncthreads();
    if (lane < 80) {
        const float* Wsc = scsT + (size_t)t*5120;
        const float* W2s = lin2sT + (size_t)t*1280;
        float a_sc = 0.f, a_2 = 0.f;
        #pragma unroll
        for (int i = 0; i < 64; ++i) a_sc += ys_l[i]*Wsc[i*80 + lane];
        #pragma unroll
        for (int i = 0; i < 16; ++i) a_2 += mids[i]*W2s[i*80 + lane];
        conv_s[lane] = 0.3826834323650898f*a_sc + 0.9238795325112867f*a_2;
    } else if (lane < 144) {
        int o = lane - 80;
        float a_si = 0.f;
        #pragma unroll
        for (int i = 0; i < 64; ++i) a_si += ys_l[i]*siWsT[i*64 + o];
        sis_l[o] = a_si;
    } else if (lane < 192) {
        int j = lane - 144, o = j/3, m = j%3;
        const float* Wsc = scvT + (size_t)t*256;
        const float* W2v = lin2vT + (size_t)t*1280;
        float a_sc = 0.f, a_2 = 0.f, a_si = 0.f;
        #pragma unroll
        for (int i = 0; i < 16; ++i) {
            float y = yv_l[i*3+m];
            a_sc += y*Wsc[i*16+o];
            a_si += y*siWvT[i*16+o];
        }
        #pragma unroll
        for (int i = 0; i < 80; ++i) a_2 += midv[i*3+m]*W2v[i*16+o];
        conv_v[j] = 0.3826834323650898f*a_sc + 0.9238795325112867f*a_2;
        siv_l[j] = a_si;
    }
    __syncthreads();
    float hh = hv[layer]; float h2c = hh*hh; float mx = mixv[layer];
    if (lane < 64) {
        float cs = conv_s[lane];
        float gns = cs/(1.f + __expf(-cs));
        float ns = 2.f*ys_l[lane] - ys_old[n*64+lane] + h2c*(mx*gns + (mx-1.f)*sis_l[lane]);
        ys_old[n*64+lane] = ns;
        ysn[lane] = ns;
    } else if (lane < 112) {
        int j = lane-64, o = j/3;
        float g = 1.f/(1.f + __expf(-conv_s[64+o]));
        float gnv = g*conv_v[j];
        float nv = 2.f*yv_l[j] - yv_old[n*48+j] + h2c*(mx*gnv + (mx-1.f)*siv_l[j]);
        yv_old[n*48+j] = nv;
        yvn[j] = nv;
    }
    __syncthreads();
    if (lane < 6) {
        int i = lane/3, m = lane%3;
        float acc = 0.f;
        #pragma unroll
        for (int u = 0; u < 16; ++u) acc += Kbuf[2*u+i]*yvn[u*3+m];
        xpad[n*8 + lane] = acc;
        if (dout) dout[n*6 + lane] = acc;
    }
    // fused next-layer lin1
    if (lane < 64) {
        const float* W = lin1sTn + (size_t)t*4096;
        float acc = 0.f;
        #pragma unroll
        for (int i = 0; i < 64; ++i) acc += ysn[i]*W[i*64 + lane];
        fs_out[n*64 + lane] = acc;
    } else if (lane < 112) {
        int j = lane - 64, o = j/3, m = j%3;
        const float* W = lin1vTn + (size_t)t*256;
        float acc = 0.f;
        #pragma unroll
        for (int i = 0; i < 16; ++i) acc += yvn[i*3+m]*W[i*16 + o];
        fvv_out[n*48 + j] = acc;
    }
}

// ---------------- host ----------------
extern "C" void kernel_launch(void* const* d_in, const int* in_sizes, int n_in,
                              void* d_out, int out_size, void* d_ws, size_t ws_size,
                              hipStream_t stream)
{
    const float* x_in   = (const float*)d_in[0];
    const int*   types  = (const int*)  d_in[2];
    const int*   esrc   = (const int*)  d_in[3];
    const int*   edst   = (const int*)  d_in[4];
    const float* emb    = (const float*)d_in[5];
    const float* PU     = (const float*)d_in[6];
    const float* hv     = (const float*)d_in[7];
    const float* mixv   = (const float*)d_in[8];
    const float* si_Ws  = (const float*)d_in[9];
    const float* si_Wv  = (const float*)d_in[10];
    const float* sc_Ws  = (const float*)d_in[11];
    const float* sc_Wv  = (const float*)d_in[12];
    const float* lin1_Ws= (const float*)d_in[13];
    const float* lin1_Wv= (const float*)d_in[14];
    const float* lin2_Ws= (const float*)d_in[15];
    const float* lin2_Wv= (const float*)d_in[16];
    const float* fc_W1  = (const float*)d_in[17];
    const float* fc_b1  = (const float*)d_in[18];
    const float* fc_W2  = (const float*)d_in[19];
    const float* fc_b2  = (const float*)d_in[20];
    const float* fc_W3  = (const float*)d_in[21];
    const float* fc_b3  = (const float*)d_in[22];

    float* ws = (float*)d_ws;
    size_t off = 0;
    auto alloc = [&](size_t nf) { float* p = ws + off; off += nf; return p; };
    float* Kbuf   = alloc(64);
    float* x_pad  = alloc(80000);
    float* ys0    = alloc(640000);
    float* ys1    = alloc(640000);
    float* yv0    = alloc(480000);
    float* yv1    = alloc(480000);
    float* fsb    = alloc(640000);
    float* fvvb   = alloc(480000);
    float* midb   = alloc((size_t)NN*256);
    float* lin1sT = alloc((size_t)4*100*4096);
    float* lin1vT = alloc((size_t)4*100*256);
    float* scsT   = alloc((size_t)4*100*5120);
    float* scvT   = alloc((size_t)4*100*256);
    float* lin2sT = alloc((size_t)4*100*1280);
    float* lin2vT = alloc((size_t)4*100*1280);
    float* siWsT  = alloc((size_t)4*4096);
    float* siWvT  = alloc((size_t)4*256);
    // int region
    int* iws = (int*)(ws + off);
    size_t ioff = 0;
    auto ialloc = [&](size_t ni) { int* p = iws + ioff; ioff += ni; return p; };
    int* deg    = ialloc(NN);
    int* segoff = ialloc(NN + 8);
    int* cursor = ialloc(NN);
    int* srcs   = ialloc(NE);
    int* dsts   = ialloc(NE);
    int* nperm  = ialloc(NN + 8);   // pad keeps bf16 region 16B-aligned
    // bf16 region (16B-aligned)
    unsigned short* w1bp = (unsigned short*)(iws + ioff);   // [L][64][32]
    unsigned short* w2bp = w1bp + (size_t)4*64*32;          // [L][64][64]
    unsigned short* w3bf = w2bp + (size_t)4*64*64;          // [L][192][64]
    unsigned short* ebuf = w3bf + (size_t)4*192*64;         // packed fp8-pair [128][NEP] ushort

    // K + weight prep + state init
    k_newton_kernel<<<1, 1, 0, stream>>>(PU, Kbuf);
    prep_kernel<<<(PREP_TOTAL + 255)/256, 256, 0, stream>>>(
        lin1_Ws, lin1_Wv, sc_Ws, sc_Wv, lin2_Ws, lin2_Wv, si_Ws, si_Wv,
        fc_W1, fc_W2, fc_W3, emb,
        lin1sT, lin1vT, scsT, scvT, lin2sT, lin2vT, siWsT, siWvT,
        w1bp, w2bp, w3bf);
    {
        int tot = NN*8 + NN*48 + NN*64;
        init_all_kernel<<<(tot + 255)/256, 256, 0, stream>>>(
            x_in, Kbuf, x_pad, yv0, yv1, ys0, ys1, fsb);
    }
    init_fvv_kernel<<<(NN*48 + 255)/256, 256, 0, stream>>>(yv0, types, lin1vT, fvvb);

    // counting sort by dst + node type-sort
    (void)hipMemsetAsync(deg, 0, NN*sizeof(int), stream);
    hist_kernel<<<(NE+255)/256, 256, 0, stream>>>(edst, deg);
    scan_kernel<<<1, 256, 0, stream>>>(deg, segoff, cursor);
    scatter_kernel<<<(NE+255)/256, 256, 0, stream>>>(esrc, edst, cursor, srcs, dsts);
    nsort_kernel<<<1, 256, 0, stream>>>(types, nperm);

    float* ys_cur = ys0; float* ys_old = ys1;
    float* yv_cur = yv0; float* yv_old = yv1;
    for (int l = 0; l < 4; ++l) {
        edge_fused_kernel<<<NE/64, 256, 0, stream>>>(
            x_pad, srcs, dsts,
            w1bp + (size_t)l*64*32,  fc_b1 + (size_t)l*64,
            w2bp + (size_t)l*64*64,  fc_b2 + (size_t)l*64,
            w3bf + (size_t)l*192*64, fc_b3 + (size_t)l*192,
            fsb, fvvb, ebuf);
        segsum_kernel<<<NN/16, 256, 0, stream>>>(ebuf, segoff, midb);
        int ln = (l + 1) & 3;
        node_update_kernel<<<NN, 256, 0, stream>>>(
            ys_cur, yv_cur, ys_old, yv_old,
            midb, types, nperm,
            scsT   + (size_t)l*100*5120, scvT   + (size_t)l*100*256,
            lin2sT + (size_t)l*100*1280, lin2vT + (size_t)l*100*1280,
            siWsT  + (size_t)l*4096,     siWvT  + (size_t)l*256,
            lin1sT + (size_t)ln*100*4096, lin1vT + (size_t)ln*100*256,
            Kbuf, hv, mixv, l, fsb, fvvb,
            x_pad, (l == 3) ? (float*)d_out : nullptr);
        float* tmp;
        tmp = ys_cur; ys_cur = ys_old; ys_old = tmp;
        tmp = yv_cur; yv_cur = yv_old; yv_old = tmp;
    }
}

// Round 18
// 1042.611 us; speedup vs baseline: 1.0209x; 1.0209x over previous
//
#include <hip/hip_runtime.h>
#include <hip/hip_fp8.h>
#include <math.h>

#define NN 10000
#define NE 320000
#define NEP (NE + 64)      // padded ebuf row stride (ushort elements)
#define PI_F 3.14159265358979323846f

typedef __attribute__((ext_vector_type(8))) short short8x;
typedef __attribute__((ext_vector_type(4))) float float4x;

#if defined(__has_builtin)
#if __has_builtin(__builtin_amdgcn_cvt_pk_fp8_f32) && __has_builtin(__builtin_amdgcn_cvt_f32_fp8)
#define HW_FP8 1
#endif
#endif

__device__ __forceinline__ unsigned short f2b(float f) {
    unsigned b = __float_as_uint(f);
    return (unsigned short)((b + 0x7FFFu + ((b >> 16) & 1u)) >> 16);
}
__device__ __forceinline__ float b2f(unsigned short u) {
    return __uint_as_float(((unsigned)u) << 16);
}
__device__ __forceinline__ float silu(float x) {
    return x / (1.f + __expf(-x));
}
__device__ __forceinline__ unsigned char f2e4(float f) {
#ifdef HW_FP8
    int r = __builtin_amdgcn_cvt_pk_fp8_f32(f, f, 0, false);
    return (unsigned char)(r & 0xff);
#else
    __hip_fp8_e4m3 q(f);
    return (unsigned char)q.__x;
#endif
}
__device__ __forceinline__ unsigned short pk2(float lo, float hi) {
#ifdef HW_FP8
    int r = __builtin_amdgcn_cvt_pk_fp8_f32(lo, hi, 0, false);
    return (unsigned short)(r & 0xffff);
#else
    return (unsigned short)((unsigned)f2e4(lo) | ((unsigned)f2e4(hi) << 8));
#endif
}
__device__ __forceinline__ float e42f(unsigned char v) {
#ifdef HW_FP8
    return __builtin_amdgcn_cvt_f32_fp8((int)v, 0);
#else
    __hip_fp8_e4m3 q;
    q.__x = (__hip_fp8_storage_t)v;
    return (float)q;
#endif
}
// byte-select decode: builtin requires IMMEDIATE sel -> switch with literal cases
__device__ __forceinline__ float e4sel(unsigned word, int sel) {
#ifdef HW_FP8
    switch (sel & 3) {
        case 0:  return __builtin_amdgcn_cvt_f32_fp8((int)word, 0);
        case 1:  return __builtin_amdgcn_cvt_f32_fp8((int)word, 1);
        case 2:  return __builtin_amdgcn_cvt_f32_fp8((int)word, 2);
        default: return __builtin_amdgcn_cvt_f32_fp8((int)word, 3);
    }
#else
    return e42f((unsigned char)((word >> (8*(sel & 3))) & 0xffu));
#endif
}

// ---------------- K = Newton-Schulz semi-unitary (16x2) ----------------
__global__ void k_newton_kernel(const float* __restrict__ PU, float* __restrict__ Kout)
{
    if (threadIdx.x != 0 || blockIdx.x != 0) return;
    float K[32];
    float nrm = 0.f;
    for (int i = 0; i < 32; ++i) { K[i] = PU[i]; nrm += K[i]*K[i]; }
    float inv = 1.0f / sqrtf(nrm);
    for (int i = 0; i < 32; ++i) K[i] *= inv;
    for (int it = 0; it < 10; ++it) {
        float m00 = 0.f, m01 = 0.f, m11 = 0.f;
        for (int u = 0; u < 16; ++u) {
            float a = K[2*u], b = K[2*u+1];
            m00 += a*a; m01 += a*b; m11 += b*b;
        }
        for (int u = 0; u < 16; ++u) {
            float a = K[2*u], b = K[2*u+1];
            K[2*u]   = 1.5f*a - 0.5f*(a*m00 + b*m01);
            K[2*u+1] = 1.5f*b - 0.5f*(a*m01 + b*m11);
        }
    }
    for (int i = 0; i < 32; ++i) Kout[i] = K[i];
}

// ---------------- merged init: x_pad + yv init + zero ys0/ys1/fsb ----------------
__global__ __launch_bounds__(256) void init_all_kernel(
    const float* __restrict__ x, const float* __restrict__ K,
    float* __restrict__ xp, float* __restrict__ yv0, float* __restrict__ yv1,
    float* __restrict__ ys0, float* __restrict__ ys1, float* __restrict__ fsb)
{
    int tid = blockIdx.x*256 + threadIdx.x;
    if (tid < NN*8) {
        int n = tid >> 3, c = tid & 7;
        xp[tid] = (c < 6) ? x[n*6 + c] : 0.f;
        return;
    }
    int t2 = tid - NN*8;
    if (t2 < NN*48) {
        int n = t2/48, j = t2%48, u = j/3, m = j%3;
        float v = K[2*u]*x[n*6+m] + K[2*u+1]*x[n*6+3+m];
        yv0[t2] = v; yv1[t2] = v;
        return;
    }
    t2 -= NN*48;
    if (t2 < NN*64) { ys0[t2] = 0.f; ys1[t2] = 0.f; fsb[t2] = 0.f; }
}

// ---------------- layer-0 fvv init (fs0 = 0 since ys0 = 0) ----------------
__global__ void init_fvv_kernel(const float* __restrict__ yv, const int* __restrict__ types,
                                const float* __restrict__ lin1vT0, float* __restrict__ fvv)
{
    int tid = blockIdx.x*blockDim.x + threadIdx.x;
    if (tid >= NN*48) return;
    int n = tid/48, j = tid%48, o = j/3, m = j%3;
    int t = types[n];
    const float* W = lin1vT0 + (size_t)t*256;
    float acc = 0.f;
    #pragma unroll
    for (int i = 0; i < 16; ++i) acc += yv[n*48 + i*3 + m]*W[i*16 + o];
    fvv[tid] = acc;
}

// ---------------- per-type effective weights (device body) ----------------
__device__ __forceinline__ void be_body(const float* __restrict__ W, const float* __restrict__ emb,
                                        float* __restrict__ out, int id, int O, int I, float scale)
{
    int o = id % O; int r = id / O;
    int i = r % I; r /= I;
    int t = r % 100; int l = r / 100;
    const float* w  = W + (((size_t)l*O + o)*I + i)*32;
    const float* em = emb + (size_t)t*32;
    float acc = 0.f;
    #pragma unroll
    for (int e = 0; e < 32; ++e) acc += w[e]*em[e];
    out[id] = acc*scale;
}

// ---------------- merged weight prep ----------------
#define PREP_TOTAL (2048000 + 1638400 + 512000 + 512000 + 102400 + 102400 + 49152 + 16384 + 16384 + 8192 + 1024)
__global__ __launch_bounds__(256) void prep_kernel(
    const float* __restrict__ lin1_Ws, const float* __restrict__ lin1_Wv,
    const float* __restrict__ sc_Ws,   const float* __restrict__ sc_Wv,
    const float* __restrict__ lin2_Ws, const float* __restrict__ lin2_Wv,
    const float* __restrict__ si_Ws,   const float* __restrict__ si_Wv,
    const float* __restrict__ fc_W1,   const float* __restrict__ fc_W2,
    const float* __restrict__ fc_W3,   const float* __restrict__ emb,
    float* __restrict__ lin1sT, float* __restrict__ lin1vT,
    float* __restrict__ scsT,   float* __restrict__ scvT,
    float* __restrict__ lin2sT, float* __restrict__ lin2vT,
    float* __restrict__ siWsT,  float* __restrict__ siWvT,
    unsigned short* __restrict__ w1bp, unsigned short* __restrict__ w2bp,
    unsigned short* __restrict__ w3bf)
{
    const float s2048 = 0.022097086912079608f;   // 1/sqrt(2048)
    const float s512  = 0.044194173824159216f;   // 1/sqrt(512)
    const float s2560 = 0.019764235376052372f;   // 1/sqrt(2560)
    int tid = blockIdx.x*256 + threadIdx.x;
    if (tid < 2048000) { be_body(sc_Ws,   emb, scsT,   tid, 80, 64, s2048); return; }
    tid -= 2048000;
    if (tid < 1638400) { be_body(lin1_Ws, emb, lin1sT, tid, 64, 64, s2048); return; }
    tid -= 1638400;
    if (tid < 512000)  { be_body(lin2_Ws, emb, lin2sT, tid, 80, 16, s512);  return; }
    tid -= 512000;
    if (tid < 512000)  { be_body(lin2_Wv, emb, lin2vT, tid, 16, 80, s2560); return; }
    tid -= 512000;
    if (tid < 102400)  { be_body(lin1_Wv, emb, lin1vT, tid, 16, 16, s512);  return; }
    tid -= 102400;
    if (tid < 102400)  { be_body(sc_Wv,   emb, scvT,   tid, 16, 16, s512);  return; }
    tid -= 102400;
    if (tid < 49152) {  // w3bf = bf16(transpose(fc_W3)): [l][n=192][k=64]
        int o = tid % 64; int r = tid / 64; int i = r % 192; int l = r / 192;
        w3bf[tid] = f2b(fc_W3[((size_t)l*64 + o)*192 + i]);
        return;
    }
    tid -= 49152;
    if (tid < 16384) {  // siWsT = 0.125 * transpose(si_Ws)
        int o = tid % 64; int r = tid / 64; int i = r % 64; int l = r / 64;
        siWsT[tid] = si_Ws[((size_t)l*64 + o)*64 + i]*0.125f;
        return;
    }
    tid -= 16384;
    if (tid < 16384) {  // w2bp: pack fc_W2 K=64,N=64,KP=64
        int kk = tid % 64; int r = tid / 64; int n = r % 64; int l = r / 64;
        w2bp[tid] = f2b(fc_W2[((size_t)l*64 + kk)*64 + n]);
        return;
    }
    tid -= 16384;
    if (tid < 8192) {   // w1bp: pack fc_W1 K=16,N=64,KP=32 (zero-pad)
        int kk = tid % 32; int r = tid / 32; int n = r % 64; int l = r / 64;
        float v = (kk < 16) ? fc_W1[((size_t)l*16 + kk)*64 + n] : 0.f;
        w1bp[tid] = f2b(v);
        return;
    }
    tid -= 8192;
    if (tid < 1024) {   // siWvT = 0.25 * transpose(si_Wv)
        int o = tid % 16; int r = tid / 16; int i = r % 16; int l = r / 16;
        siWvT[tid] = si_Wv[((size_t)l*16 + o)*16 + i]*0.25f;
    }
}

// ---------------- counting sort by dst ----------------
__global__ void hist_kernel(const int* __restrict__ dst, int* __restrict__ deg)
{
    int e = blockIdx.x*256 + threadIdx.x;
    if (e < NE) atomicAdd(&deg[dst[e]], 1);
}

__global__ __launch_bounds__(256) void scan_kernel(const int* __restrict__ deg,
                                                   int* __restrict__ segoff,
                                                   int* __restrict__ cursor)
{
    __shared__ int part[256];
    int tid = threadIdx.x;
    int base = tid*40;
    int s = 0;
    for (int i = 0; i < 40; ++i) { int idx = base+i; if (idx < NN) s += deg[idx]; }
    part[tid] = s;
    __syncthreads();
    for (int o = 1; o < 256; o <<= 1) {
        int v = (tid >= o) ? part[tid-o] : 0;
        __syncthreads();
        part[tid] += v;
        __syncthreads();
    }
    int excl = part[tid] - s;
    for (int i = 0; i < 40; ++i) {
        int idx = base+i;
        if (idx < NN) { segoff[idx] = excl; cursor[idx] = excl; excl += deg[idx]; }
        else if (idx == NN) { segoff[NN] = excl; }
    }
}

__global__ void scatter_kernel(const int* __restrict__ src, const int* __restrict__ dst,
                               int* __restrict__ cursor,
                               int* __restrict__ srcs, int* __restrict__ dsts)
{
    int e = blockIdx.x*256 + threadIdx.x;
    if (e >= NE) return;
    int d = dst[e];
    int p = atomicAdd(&cursor[d], 1);
    srcs[p] = src[e]; dsts[p] = d;
}

// ---------------- fused edge kernel: geometry -> MFMA MLP chain -> TP -> ebuf ----------------
// ebuf layout: 128 ushort rows; row r packs fp8(comp 2r) | fp8(comp 2r+1)<<8.
__global__ __launch_bounds__(256, 8) void edge_fused_kernel(
    const float* __restrict__ xp,
    const int* __restrict__ srcs, const int* __restrict__ dsts,
    const unsigned short* __restrict__ w1b,   // [64 n][32 k] bf16 (k 16..31 zero)
    const float* __restrict__ b1,
    const unsigned short* __restrict__ w2b,   // [64 n][64 k] bf16
    const float* __restrict__ b2,
    const unsigned short* __restrict__ w3b,   // [192 n][64 k] bf16
    const float* __restrict__ b3,
    const float* __restrict__ fs, const float* __restrict__ fvv,
    unsigned short* __restrict__ ebuf)
{
    __shared__ __align__(16) unsigned char smem[64*196];   // wbuf fp8 region; hbuf aliases front
    __shared__ float abuf[64*6];
    unsigned short* hbuf = (unsigned short*)smem;          // [64][72] bf16 (9216 B)
    unsigned char*  wbuf = smem;                           // [64][196] fp8 (12544 B)
    int lane = threadIdx.x & 63;
    int wid  = threadIdx.x >> 6;
    int eblk = blockIdx.x * 64;
    int row16 = lane & 15, quad = lane >> 4;
    int erow = 16*wid + row16;

    // ---- phase G: lanes 0..15 of each wave: geometry ----
    if (lane < 16) {
        int p = eblk + 16*wid + lane;
        int s = srcs[p], d = dsts[p];
        const float4* xs4 = (const float4*)(xp + (size_t)s*8);
        const float4* xd4 = (const float4*)(xp + (size_t)d*8);
        float4 xsa = xs4[0], xsb = xs4[1];
        float4 xda = xd4[0], xdb = xd4[1];
        float a0[3], a1[3], ef[16];
        {
            float d0 = xsa.x-xda.x, d1 = xsa.y-xda.y, d2 = xsa.z-xda.z;
            float r = sqrtf(d0*d0 + d1*d1 + d2*d2);
            float invr = 1.0f/r;
            float u = 0.8f*r - 2.0f;
            float cut = (u > 0.f) ? 0.f : ((u < -1.f) ? 1.f : 0.5f*(1.f - __cosf(PI_F*u)));
            float sc = 1.7320508075688772f*cut*invr;
            a0[0] = sc*d0; a0[1] = sc*d1; a0[2] = sc*d2;
            float fsc = 2.5298221281347035f*invr;
            #pragma unroll
            for (int k = 0; k < 8; ++k) ef[k] = fsc*__sinf((k+1)*1.2566370614359172f*r);
        }
        {
            float d0 = xsa.w-xda.w, d1 = xsb.x-xdb.x, d2 = xsb.y-xdb.y;
            float r = sqrtf(d0*d0 + d1*d1 + d2*d2);
            float invr = 1.0f/r;
            float u = 0.8f*r - 2.0f;
            float cut = (u > 0.f) ? 0.f : ((u < -1.f) ? 1.f : 0.5f*(1.f - __cosf(PI_F*u)));
            float sc = 1.7320508075688772f*cut*invr;
            a1[0] = sc*d0; a1[1] = sc*d1; a1[2] = sc*d2;
            float fsc = 2.5298221281347035f*invr;
            #pragma unroll
            for (int k = 0; k < 8; ++k) ef[8+k] = fsc*__sinf((k+1)*1.2566370614359172f*r);
        }
        float* ab = abuf + (16*wid + lane)*6;
        ab[0] = a0[0]; ab[1] = a0[1]; ab[2] = a0[2];
        ab[3] = a1[0]; ab[4] = a1[1]; ab[5] = a1[2];
        unsigned epk[8];
        #pragma unroll
        for (int k = 0; k < 8; ++k)
            epk[k] = (unsigned)f2b(ef[2*k]) | ((unsigned)f2b(ef[2*k+1]) << 16);
        uint4* hr = (uint4*)(hbuf + (16*wid + lane)*72);
        uint4 q0; q0.x = epk[0]; q0.y = epk[1]; q0.z = epk[2]; q0.w = epk[3];
        uint4 q1; q1.x = epk[4]; q1.y = epk[5]; q1.z = epk[6]; q1.w = epk[7];
        uint4 qz; qz.x = 0; qz.y = 0; qz.z = 0; qz.w = 0;
        hr[0] = q0; hr[1] = q1; hr[2] = qz; hr[3] = qz;
    }
    // hbuf rows are wave-exclusive; per-wave DS ordering suffices

    // ---- GEMM1: h1 = silu(ef @ W1 + b1), K=32 ----
    {
        short8x a = *(const short8x*)(hbuf + erow*72 + quad*8);
        float4x c[4];
        #pragma unroll
        for (int nt = 0; nt < 4; ++nt) {
            short8x b = *(const short8x*)(w1b + ((size_t)(nt*16 + row16))*32 + quad*8);
            c[nt] = __builtin_amdgcn_mfma_f32_16x16x32_bf16(a, b, (float4x){0.f,0.f,0.f,0.f}, 0, 0, 0);
        }
        #pragma unroll
        for (int nt = 0; nt < 4; ++nt) {
            float bias = b1[nt*16 + row16];
            #pragma unroll
            for (int r = 0; r < 4; ++r) {
                float h = silu(c[nt][r] + bias);
                hbuf[(16*wid + quad*4 + r)*72 + nt*16 + row16] = f2b(h);
            }
        }
    }
    // ---- GEMM2: h2 = silu(h1 @ W2 + b2), K=64 ----
    {
        short8x a0v = *(const short8x*)(hbuf + erow*72 + 0*32 + quad*8);
        short8x a1v = *(const short8x*)(hbuf + erow*72 + 1*32 + quad*8);
        float4x c[4];
        #pragma unroll
        for (int nt = 0; nt < 4; ++nt) {
            short8x b0 = *(const short8x*)(w2b + ((size_t)(nt*16 + row16))*64 + 0*32 + quad*8);
            float4x t = __builtin_amdgcn_mfma_f32_16x16x32_bf16(a0v, b0, (float4x){0.f,0.f,0.f,0.f}, 0, 0, 0);
            short8x b1v = *(const short8x*)(w2b + ((size_t)(nt*16 + row16))*64 + 1*32 + quad*8);
            c[nt] = __builtin_amdgcn_mfma_f32_16x16x32_bf16(a1v, b1v, t, 0, 0, 0);
        }
        #pragma unroll
        for (int nt = 0; nt < 4; ++nt) {
            float bias = b2[nt*16 + row16];
            #pragma unroll
            for (int r = 0; r < 4; ++r) {
                float h = silu(c[nt][r] + bias);
                hbuf[(16*wid + quad*4 + r)*72 + nt*16 + row16] = f2b(h);
            }
        }
    }
    // ---- GEMM3: w = h2 @ W3 -> fp8 into wbuf (aliases hbuf; pre-read A then barrier) ----
    {
        short8x a0v = *(const short8x*)(hbuf + erow*72 + 0*32 + quad*8);
        short8x a1v = *(const short8x*)(hbuf + erow*72 + 1*32 + quad*8);
        __syncthreads();   // all waves hold their A-fragments; hbuf region may now be overwritten
        float4x acc[12];
        #pragma unroll
        for (int nt = 0; nt < 12; ++nt) {
            short8x b0 = *(const short8x*)(w3b + ((size_t)(nt*16 + row16))*64 + 0*32 + quad*8);
            float4x t = __builtin_amdgcn_mfma_f32_16x16x32_bf16(a0v, b0, (float4x){0.f,0.f,0.f,0.f}, 0, 0, 0);
            short8x b1v = *(const short8x*)(w3b + ((size_t)(nt*16 + row16))*64 + 1*32 + quad*8);
            acc[nt] = __builtin_amdgcn_mfma_f32_16x16x32_bf16(a1v, b1v, t, 0, 0, 0);
        }
        #pragma unroll
        for (int nt = 0; nt < 12; ++nt) {
            #pragma unroll
            for (int r = 0; r < 4; ++r) {
                wbuf[(16*wid + quad*4 + r)*196 + nt*16 + row16] = f2e4(acc[nt][r]);
            }
        }
    }
    __syncthreads();

    // ---- TP phase: thread (edge = lane, part = wid) ----
    int p = eblk + lane;
    const unsigned* wrow32 = (const unsigned*)(wbuf + lane*196);  // 196 % 4 == 0
    float a0[3], a1[3];
    {
        const float* ab = abuf + lane*6;
        a0[0] = ab[0]; a0[1] = ab[1]; a0[2] = ab[2];
        a1[0] = ab[3]; a1[1] = ab[4]; a1[2] = ab[5];
    }
    int s = srcs[p];
    // o1: comps [48*wid, 48*wid+48) -> pair rows [24*wid, 24*wid+24)
    {
        int U0 = 16*wid;
        int rbase = 24*wid;
        float fsr[16];
        {
            const float4* f4 = (const float4*)(fs + (size_t)s*64 + U0);
            #pragma unroll
            for (int g = 0; g < 4; ++g) {
                float4 t = f4[g];
                fsr[4*g+0] = t.x; fsr[4*g+1] = t.y; fsr[4*g+2] = t.z; fsr[4*g+3] = t.w;
            }
        }
        float carry = 0.f;
        #pragma unroll
        for (int uu = 0; uu < 16; ++uu) {
            int u = U0 + uu;
            float su = fsr[uu]*0.125f;   // 1/sqrt(2) * 1/sqrt(32)
            unsigned word = wrow32[u >> 1];
            float wa = e4sel(word, (uu & 1)*2)     + b3[2*u];
            float wb = e4sel(word, (uu & 1)*2 + 1) + b3[2*u+1];
            float q0 = su*(wa*a0[0] + wb*a1[0]);
            float q1 = su*(wa*a0[1] + wb*a1[1]);
            float q2 = su*(wa*a0[2] + wb*a1[2]);
            if ((uu & 1) == 0) {
                ebuf[(size_t)(rbase + (3*uu)/2)*NEP + p] = pk2(q0, q1);
                carry = q2;
            } else {
                ebuf[(size_t)(rbase + (3*uu-1)/2)*NEP + p] = pk2(carry, q0);
                ebuf[(size_t)(rbase + (3*uu+1)/2)*NEP + p] = pk2(q1, q2);
            }
        }
    }
    // o2 + o3
    {
        int U0 = 4*wid;
        float fvr[12];
        {
            const float4* f4 = (const float4*)(fvv + (size_t)s*48 + 3*U0);
            #pragma unroll
            for (int g = 0; g < 3; ++g) {
                float4 t = f4[g];
                fvr[4*g+0] = t.x; fvr[4*g+1] = t.y; fvr[4*g+2] = t.z; fvr[4*g+3] = t.w;
            }
        }
        int r2base = 96 + 2*wid;
        int r3base = 104 + 6*wid;
        float o2v[4];
        float carry = 0.f;
        #pragma unroll
        for (int uu = 0; uu < 4; ++uu) {
            int u = U0 + uu;
            float v0 = fvr[uu*3+0], v1 = fvr[uu*3+1], v2 = fvr[uu*3+2];
            unsigned w2w = wrow32[32 + (u >> 1)];
            unsigned w3w = wrow32[40 + (u >> 1)];
            float w2a = e4sel(w2w, (uu & 1)*2)     + b3[128+2*u];
            float w2b = e4sel(w2w, (uu & 1)*2 + 1) + b3[129+2*u];
            float w3a = e4sel(w3w, (uu & 1)*2)     + b3[160+2*u];
            float w3b = e4sel(w3w, (uu & 1)*2 + 1) + b3[161+2*u];
            float dd0 = v0*a0[0] + v1*a0[1] + v2*a0[2];
            float dd1 = v0*a1[0] + v1*a1[1] + v2*a1[2];
            o2v[uu] = (w2a*dd0 + w2b*dd1)*0.07216878364870323f;  // 1/sqrt(192)
            float c0x = v1*a0[2]-v2*a0[1], c0y = v2*a0[0]-v0*a0[2], c0z = v0*a0[1]-v1*a0[0];
            float c1x = v1*a1[2]-v2*a1[1], c1y = v2*a1[0]-v0*a1[2], c1z = v0*a1[1]-v1*a1[0];
            float q0 = 0.08838834764831845f*(w3a*c0x + w3b*c1x);  // 1/sqrt(128)
            float q1 = 0.08838834764831845f*(w3a*c0y + w3b*c1y);
            float q2 = 0.08838834764831845f*(w3a*c0z + w3b*c1z);
            if ((uu & 1) == 0) {
                ebuf[(size_t)(r3base + (3*uu)/2)*NEP + p] = pk2(q0, q1);
                carry = q2;
            } else {
                ebuf[(size_t)(r3base + (3*uu-1)/2)*NEP + p] = pk2(carry, q0);
                ebuf[(size_t)(r3base + (3*uu+1)/2)*NEP + p] = pk2(q1, q2);
            }
        }
        ebuf[(size_t)(r2base + 0)*NEP + p] = pk2(o2v[0], o2v[1]);
        ebuf[(size_t)(r2base + 1)*NEP + p] = pk2(o2v[2], o2v[3]);
    }
}

// ---------------- segment-sum via LDS transpose tiles (packed fp8-pair rows, pairwise scan) ----------------
__global__ __launch_bounds__(256) void segsum_kernel(
    const unsigned short* __restrict__ ebuf,
    const int* __restrict__ segoff,
    float* __restrict__ mid)
{
    __shared__ int sbnd[18];
    __shared__ unsigned short stile[256*66];
    int c = threadIdx.x;
    int lane = c & 63, wid = c >> 6;
    int n0 = blockIdx.x * 16;
    if (c < 17) sbnd[c] = segoff[n0 + c];
    else if (c == 17) sbnd[17] = 0x7fffffff;   // sentinel
    __syncthreads();
    int P0 = sbnd[0], P1 = sbnd[16];
    int A = P0 & ~63;
    float cur = 0.f;
    int seg = 0;
    int bnext = sbnd[1];
    const unsigned short* row = stile + c*66;
    for (int base = A; base < P1; base += 64) {
        {
            // wave wid stages packed rows [32*wid, 32*wid+32) -> stile comp rows [64*wid, 64*wid+64)
            const unsigned short* src = ebuf + (size_t)(32*wid)*NEP + base + lane;
            unsigned short* dst = stile + (64*wid)*66 + lane;
            #pragma unroll
            for (int rr = 0; rr < 32; ++rr) {
                unsigned v = (unsigned)src[(size_t)rr*NEP];
                dst[(2*rr  )*66] = f2b(e4sel(v, 0));
                dst[(2*rr+1)*66] = f2b(e4sel(v, 1));
            }
        }
        __syncthreads();
        int e0 = (base < P0) ? P0 : base;
        int e1 = (base + 64 < P1) ? (base + 64) : P1;
        int e = e0;
        while (e < e1) {
            int stop = (bnext < e1) ? bnext : e1;
            if (((e - base) & 1) && e < stop) { cur += b2f(row[e - base]); ++e; }
            for (; e + 2 <= stop; e += 2) {
                unsigned v = *(const unsigned*)(row + (e - base));   // 2 edges per b32 read
                cur += b2f((unsigned short)(v & 0xffffu)) + b2f((unsigned short)(v >> 16));
            }
            if (e < stop) { cur += b2f(row[e - base]); ++e; }
            if (e == bnext) {    // segment complete (wave-uniform)
                mid[(size_t)(n0 + seg)*256 + c] = cur;
                cur = 0.f; ++seg; bnext = sbnd[seg + 1];
            }
        }
        __syncthreads();
    }
    while (seg < 16) {
        mid[(size_t)(n0 + seg)*256 + c] = cur;
        cur = 0.f; ++seg;
    }
}

// ---------------- node update + fused next-layer lin1 ----------------
__global__ __launch_bounds__(256) void node_update_kernel(
    const float* __restrict__ ys, const float* __restrict__ yv,
    float* __restrict__ ys_old, float* __restrict__ yv_old,
    const float* __restrict__ mid,
    const int* __restrict__ types,
    const float* __restrict__ scsT, const float* __restrict__ scvT,
    const float* __restrict__ lin2sT, const float* __restrict__ lin2vT,
    const float* __restrict__ siWsT, const float* __restrict__ siWvT,
    const float* __restrict__ lin1sTn, const float* __restrict__ lin1vTn, // next layer
    const float* __restrict__ Kbuf,
    const float* __restrict__ hv, const float* __restrict__ mixv, int layer,
    float* __restrict__ fs_out, float* __restrict__ fvv_out,
    float* __restrict__ xpad, float* __restrict__ dout)
{
    int n = blockIdx.x;
    int lane = threadIdx.x;
    __shared__ float ys_l[64], yv_l[48], mids[16], midv[240];
    __shared__ float conv_s[80], conv_v[48], sis_l[64], siv_l[48], ysn[64], yvn[48];
    int t = types[n];
    {
        float v = mid[(size_t)n*256 + lane];
        if (lane < 192) midv[lane] = v;
        else if (lane < 208) mids[lane-192] = v;
        else midv[192 + (lane-208)] = v;
    }
    if (lane < 64) ys_l[lane] = ys[n*64 + lane];
    else if (lane < 112) yv_l[lane-64] = yv[n*48 + (lane-64)];
    __syncthreads();
    if (lane < 80) {
        const float* Wsc = scsT + (size_t)t*5120;
        const float* W2s = lin2sT + (size_t)t*1280;
        float a_sc = 0.f, a_2 = 0.f;
        #pragma unroll
        for (int i = 0; i < 64; ++i) a_sc += ys_l[i]*Wsc[i*80 + lane];
        #pragma unroll
        for (int i = 0; i < 16; ++i) a_2 += mids[i]*W2s[i*80 + lane];
        conv_s[lane] = 0.3826834323650898f*a_sc + 0.9238795325112867f*a_2;
    } else if (lane < 144) {
        int o = lane - 80;
        float a_si = 0.f;
        #pragma unroll
        for (int i = 0; i < 64; ++i) a_si += ys_l[i]*siWsT[i*64 + o];
        sis_l[o] = a_si;
    } else if (lane < 192) {
        int j = lane - 144, o = j/3, m = j%3;
        const float* Wsc = scvT + (size_t)t*256;
        const float* W2v = lin2vT + (size_t)t*1280;
        float a_sc = 0.f, a_2 = 0.f, a_si = 0.f;
        #pragma unroll
        for (int i = 0; i < 16; ++i) {
            float y = yv_l[i*3+m];
            a_sc += y*Wsc[i*16+o];
            a_si += y*siWvT[i*16+o];
        }
        #pragma unroll
        for (int i = 0; i < 80; ++i) a_2 += midv[i*3+m]*W2v[i*16+o];
        conv_v[j] = 0.3826834323650898f*a_sc + 0.9238795325112867f*a_2;
        siv_l[j] = a_si;
    }
    __syncthreads();
    float hh = hv[layer]; float h2c = hh*hh; float mx = mixv[layer];
    if (lane < 64) {
        float cs = conv_s[lane];
        float gns = cs/(1.f + __expf(-cs));
        float ns = 2.f*ys_l[lane] - ys_old[n*64+lane] + h2c*(mx*gns + (mx-1.f)*sis_l[lane]);
        ys_old[n*64+lane] = ns;
        ysn[lane] = ns;
    } else if (lane < 112) {
        int j = lane-64, o = j/3;
        float g = 1.f/(1.f + __expf(-conv_s[64+o]));
        float gnv = g*conv_v[j];
        float nv = 2.f*yv_l[j] - yv_old[n*48+j] + h2c*(mx*gnv + (mx-1.f)*siv_l[j]);
        yv_old[n*48+j] = nv;
        yvn[j] = nv;
    }
    __syncthreads();
    if (lane < 6) {
        int i = lane/3, m = lane%3;
        float acc = 0.f;
        #pragma unroll
        for (int u = 0; u < 16; ++u) acc += Kbuf[2*u+i]*yvn[u*3+m];
        xpad[n*8 + lane] = acc;
        if (dout) dout[n*6 + lane] = acc;
    }
    // fused next-layer lin1
    if (lane < 64) {
        const float* W = lin1sTn + (size_t)t*4096;
        float acc = 0.f;
        #pragma unroll
        for (int i = 0; i < 64; ++i) acc += ysn[i]*W[i*64 + lane];
        fs_out[n*64 + lane] = acc;
    } else if (lane < 112) {
        int j = lane - 64, o = j/3, m = j%3;
        const float* W = lin1vTn + (size_t)t*256;
        float acc = 0.f;
        #pragma unroll
        for (int i = 0; i < 16; ++i) acc += yvn[i*3+m]*W[i*16 + o];
        fvv_out[n*48 + j] = acc;
    }
}

// ---------------- host ----------------
extern "C" void kernel_launch(void* const* d_in, const int* in_sizes, int n_in,
                              void* d_out, int out_size, void* d_ws, size_t ws_size,
                              hipStream_t stream)
{
    const float* x_in   = (const float*)d_in[0];
    const int*   types  = (const int*)  d_in[2];
    const int*   esrc   = (const int*)  d_in[3];
    const int*   edst   = (const int*)  d_in[4];
    const float* emb    = (const float*)d_in[5];
    const float* PU     = (const float*)d_in[6];
    const float* hv     = (const float*)d_in[7];
    const float* mixv   = (const float*)d_in[8];
    const float* si_Ws  = (const float*)d_in[9];
    const float* si_Wv  = (const float*)d_in[10];
    const float* sc_Ws  = (const float*)d_in[11];
    const float* sc_Wv  = (const float*)d_in[12];
    const float* lin1_Ws= (const float*)d_in[13];
    const float* lin1_Wv= (const float*)d_in[14];
    const float* lin2_Ws= (const float*)d_in[15];
    const float* lin2_Wv= (const float*)d_in[16];
    const float* fc_W1  = (const float*)d_in[17];
    const float* fc_b1  = (const float*)d_in[18];
    const float* fc_W2  = (const float*)d_in[19];
    const float* fc_b2  = (const float*)d_in[20];
    const float* fc_W3  = (const float*)d_in[21];
    const float* fc_b3  = (const float*)d_in[22];

    float* ws = (float*)d_ws;
    size_t off = 0;
    auto alloc = [&](size_t nf) { float* p = ws + off; off += nf; return p; };
    float* Kbuf   = alloc(64);
    float* x_pad  = alloc(80000);
    float* ys0    = alloc(640000);
    float* ys1    = alloc(640000);
    float* yv0    = alloc(480000);
    float* yv1    = alloc(480000);
    float* fsb    = alloc(640000);
    float* fvvb   = alloc(480000);
    float* midb   = alloc((size_t)NN*256);
    float* lin1sT = alloc((size_t)4*100*4096);
    float* lin1vT = alloc((size_t)4*100*256);
    float* scsT   = alloc((size_t)4*100*5120);
    float* scvT   = alloc((size_t)4*100*256);
    float* lin2sT = alloc((size_t)4*100*1280);
    float* lin2vT = alloc((size_t)4*100*1280);
    float* siWsT  = alloc((size_t)4*4096);
    float* siWvT  = alloc((size_t)4*256);
    // int region
    int* iws = (int*)(ws + off);
    size_t ioff = 0;
    auto ialloc = [&](size_t ni) { int* p = iws + ioff; ioff += ni; return p; };
    int* deg    = ialloc(NN);
    int* segoff = ialloc(NN + 8);
    int* cursor = ialloc(NN);
    int* srcs   = ialloc(NE);
    int* dsts   = ialloc(NE);
    // bf16 region (16B-aligned)
    unsigned short* w1bp = (unsigned short*)(iws + ioff);   // [L][64][32]
    unsigned short* w2bp = w1bp + (size_t)4*64*32;          // [L][64][64]
    unsigned short* w3bf = w2bp + (size_t)4*64*64;          // [L][192][64]
    unsigned short* ebuf = w3bf + (size_t)4*192*64;         // packed fp8-pair [128][NEP] ushort

    // K + weight prep + state init
    k_newton_kernel<<<1, 1, 0, stream>>>(PU, Kbuf);
    prep_kernel<<<(PREP_TOTAL + 255)/256, 256, 0, stream>>>(
        lin1_Ws, lin1_Wv, sc_Ws, sc_Wv, lin2_Ws, lin2_Wv, si_Ws, si_Wv,
        fc_W1, fc_W2, fc_W3, emb,
        lin1sT, lin1vT, scsT, scvT, lin2sT, lin2vT, siWsT, siWvT,
        w1bp, w2bp, w3bf);
    {
        int tot = NN*8 + NN*48 + NN*64;
        init_all_kernel<<<(tot + 255)/256, 256, 0, stream>>>(
            x_in, Kbuf, x_pad, yv0, yv1, ys0, ys1, fsb);
    }
    init_fvv_kernel<<<(NN*48 + 255)/256, 256, 0, stream>>>(yv0, types, lin1vT, fvvb);

    // counting sort by dst
    (void)hipMemsetAsync(deg, 0, NN*sizeof(int), stream);
    hist_kernel<<<(NE+255)/256, 256, 0, stream>>>(edst, deg);
    scan_kernel<<<1, 256, 0, stream>>>(deg, segoff, cursor);
    scatter_kernel<<<(NE+255)/256, 256, 0, stream>>>(esrc, edst, cursor, srcs, dsts);

    float* ys_cur = ys0; float* ys_old = ys1;
    float* yv_cur = yv0; float* yv_old = yv1;
    for (int l = 0; l < 4; ++l) {
        edge_fused_kernel<<<NE/64, 256, 0, stream>>>(
            x_pad, srcs, dsts,
            w1bp + (size_t)l*64*32,  fc_b1 + (size_t)l*64,
            w2bp + (size_t)l*64*64,  fc_b2 + (size_t)l*64,
            w3bf + (size_t)l*192*64, fc_b3 + (size_t)l*192,
            fsb, fvvb, ebuf);
        segsum_kernel<<<NN/16, 256, 0, stream>>>(ebuf, segoff, midb);
        int ln = (l + 1) & 3;   // next-layer lin1 weights (l=3: dummy but valid)
        node_update_kernel<<<NN, 256, 0, stream>>>(
            ys_cur, yv_cur, ys_old, yv_old,
            midb, types,
            scsT   + (size_t)l*100*5120, scvT   + (size_t)l*100*256,
            lin2sT + (size_t)l*100*1280, lin2vT + (size_t)l*100*1280,
            siWsT  + (size_t)l*4096,     siWvT  + (size_t)l*256,
            lin1sT + (size_t)ln*100*4096, lin1vT + (size_t)ln*100*256,
            Kbuf, hv, mixv, l, fsb, fvvb,
            x_pad, (l == 3) ? (float*)d_out : nullptr);
        float* tmp;
        tmp = ys_cur; ys_cur = ys_old; ys_old = tmp;
        tmp = yv_cur; yv_cur = yv_old; yv_old = tmp;
    }
}